// Round 7
// baseline (2413.394 us; speedup 1.0000x reference)
//
#include <hip/hip_runtime.h>
#include <math.h>

#define NT 17
#define KCAP 300
#define NITER 30
#define NQ 5        // ceil(KCAP/64)
#define LUMAX 1024  // max rows per type
// -1/tau * log2(e): sinkhorn runs in base-2 log domain
#define MSCALE2 28.853900817779268f

typedef unsigned long long u64;

#define EX2(x) __builtin_amdgcn_exp2f(x)
#define LG2(x) __builtin_amdgcn_logf(x)

// ---- meta layout (ints at ws start, zeroed each launch) ----
// [0..16]   typeCount
// [32..48]  typeOff
// [64..95]  scatterCnt
// [96]      doneFlag

__device__ inline u64 packf2(float m, float s) {
  return ((u64)__float_as_uint(s) << 32) | (u64)__float_as_uint(m);
}
__device__ inline float plo(u64 p) { return __uint_as_float((unsigned)p); }
__device__ inline float phi(u64 p) { return __uint_as_float((unsigned)(p >> 32)); }

__device__ inline float selu_f(float x) {
  const float scale = 1.0507009873554804934193349852946f;
  const float alpha = 1.6732632423543772848170429916717f;
  return x > 0.f ? scale * x : scale * alpha * (EX2(x * 1.4426950408889634f) - 1.f);
}

__global__ void k_hist(const int* __restrict__ jt, int n, int* meta) {
  int i = blockIdx.x * 256 + threadIdx.x;
  if (i < n) atomicAdd(&meta[jt[i]], 1);
  __syncthreads();
  if (threadIdx.x == 0) {
    __threadfence();
    int d = atomicAdd(&meta[96], 1);
    if (d == (int)gridDim.x - 1) {
      int off = 0;
      for (int t = 0; t < NT; t++) {
        int c = __hip_atomic_load(&meta[t], __ATOMIC_RELAXED, __HIP_MEMORY_SCOPE_AGENT);
        meta[32 + t] = off;
        off += c;
      }
      __threadfence();
    }
  }
}

__global__ void k_scatter(const int* __restrict__ jt, int n, int* meta,
                          int* __restrict__ perm, int* __restrict__ tys) {
  int i = blockIdx.x * 256 + threadIdx.x;
  if (i < n) {
    int t = jt[i];
    int pos = meta[32 + t] + atomicAdd(&meta[64 + t], 1);
    perm[pos] = i;
    tys[pos] = t;
  }
}

// h = selu(emb @ W1 + b1)   (n x D) @ (D x H)
__global__ __launch_bounds__(256) void k_hgemm(const float* __restrict__ A,
    const float* __restrict__ B, const float* __restrict__ bias,
    float* __restrict__ C, int n, int D, int H) {
  __shared__ __align__(16) float As[16][68];
  __shared__ __align__(16) float Bs[16][68];
  int tid = threadIdx.x;
  int i0 = blockIdx.x * 64, j0 = blockIdx.y * 64;
  int tx = tid & 15, ty = tid >> 4;
  int aI = tid & 63, aK = (tid >> 6) << 2;
  int bJ = (tid & 15) << 2, bK = tid >> 4;
  float acc[4][4] = {};
  for (int k0 = 0; k0 < D; k0 += 16) {
    float4 av = *(const float4*)(A + (size_t)(i0 + aI) * D + k0 + aK);
    float4 bv = *(const float4*)(B + (size_t)(k0 + bK) * H + j0 + bJ);
    __syncthreads();
    As[aK + 0][aI] = av.x; As[aK + 1][aI] = av.y; As[aK + 2][aI] = av.z; As[aK + 3][aI] = av.w;
    *(float4*)(&Bs[bK][bJ]) = bv;
    __syncthreads();
#pragma unroll
    for (int kk = 0; kk < 16; kk++) {
      float4 a4 = *(float4*)(&As[kk][ty << 2]);
      float4 b4 = *(float4*)(&Bs[kk][tx << 2]);
      float aa[4] = {a4.x, a4.y, a4.z, a4.w};
      float bb[4] = {b4.x, b4.y, b4.z, b4.w};
#pragma unroll
      for (int p = 0; p < 4; p++)
#pragma unroll
        for (int q = 0; q < 4; q++)
          acc[p][q] = fmaf(aa[p], bb[q], acc[p][q]);
    }
  }
#pragma unroll
  for (int p = 0; p < 4; p++) {
    int i = i0 + (ty << 2) + p;
    float o[4];
#pragma unroll
    for (int q = 0; q < 4; q++) {
      int j = j0 + (tx << 2) + q;
      o[q] = selu_f(acc[p][q] + bias[j]);
    }
    *(float4*)(C + (size_t)i * H + j0 + (tx << 2)) = make_float4(o[0], o[1], o[2], o[3]);
  }
}

// row norms of h (n rows) and prototypes (k rows)
__global__ __launch_bounds__(256) void k_norms(const float* __restrict__ h,
    const float* __restrict__ P, float* __restrict__ hsq, float* __restrict__ psq,
    int n, int H, int k) {
  int wv = threadIdx.x >> 6, lane = threadIdx.x & 63;
  int idx = blockIdx.x * 4 + wv;
  const float* src; float* dst;
  if (idx < n) { src = h + (size_t)idx * H; dst = hsq + idx; }
  else if (idx < n + k) { int j = idx - n; src = P + (size_t)j * H; dst = psq + j; }
  else return;
  float s = 0.f;
  for (int d = lane * 4; d < H; d += 256) {
    float4 v = *(const float4*)(src + d);
    s += v.x * v.x + v.y * v.y + v.z * v.z + v.w * v.w;
  }
#pragma unroll
  for (int o = 32; o; o >>= 1) s += __shfl_xor(s, o);
  if (lane == 0) *dst = s;
}

// Ms[r][j] = -max(0, hsq+psq-2*dot)/tau * log2(e)  (base-2 domain), rows type-sorted
__global__ __launch_bounds__(256) void k_msort(const float* __restrict__ h,
    const float* __restrict__ P, const float* __restrict__ hsq,
    const float* __restrict__ psq, const int* __restrict__ perm,
    float* __restrict__ Ms, int n, int H, int k) {
  __shared__ __align__(16) float As[16][68];
  __shared__ __align__(16) float Bs[16][68];
  __shared__ int gIdx[64];
  int tid = threadIdx.x;
  int i0 = blockIdx.x * 64, j0 = blockIdx.y * 64;
  if (tid < 64) gIdx[tid] = perm[i0 + tid];
  __syncthreads();
  int tx = tid & 15, ty = tid >> 4;
  int aI = tid & 63, aK = (tid >> 6) << 2;
  int gA = gIdx[aI];
  bool bok = (j0 + aI) < k;
  const float* bRow = P + (size_t)(j0 + (bok ? aI : 0)) * H;
  float acc[4][4] = {};
  for (int k0 = 0; k0 < H; k0 += 16) {
    float4 av = *(const float4*)(h + (size_t)gA * H + k0 + aK);
    float4 bv = *(const float4*)(bRow + k0 + aK);
    __syncthreads();
    As[aK + 0][aI] = av.x; As[aK + 1][aI] = av.y; As[aK + 2][aI] = av.z; As[aK + 3][aI] = av.w;
    Bs[aK + 0][aI] = bv.x; Bs[aK + 1][aI] = bv.y; Bs[aK + 2][aI] = bv.z; Bs[aK + 3][aI] = bv.w;
    __syncthreads();
#pragma unroll
    for (int kk = 0; kk < 16; kk++) {
      float4 a4 = *(float4*)(&As[kk][ty << 2]);
      float4 b4 = *(float4*)(&Bs[kk][tx << 2]);
      float aa[4] = {a4.x, a4.y, a4.z, a4.w};
      float bb[4] = {b4.x, b4.y, b4.z, b4.w};
#pragma unroll
      for (int p = 0; p < 4; p++)
#pragma unroll
        for (int q = 0; q < 4; q++)
          acc[p][q] = fmaf(aa[p], bb[q], acc[p][q]);
    }
  }
#pragma unroll
  for (int p = 0; p < 4; p++) {
    int rr = (ty << 2) + p;
    int r = i0 + rr;
    float hq = hsq[gIdx[rr]];
#pragma unroll
    for (int q = 0; q < 4; q++) {
      int j = j0 + (tx << 2) + q;
      if (j < k) {
        float d2 = hq + psq[j] - 2.f * acc[p][q];
        d2 = fmaxf(d2, 0.f);
        Ms[(size_t)r * k + j] = -d2 * MSCALE2;
      }
    }
  }
}

// Persistent Sinkhorn, base-2 log domain. ONE TYPE PER BLOCK (17 blocks x 1024).
// M (type slab, ~430KB) streamed from L2 once per iteration into 8-row x 5-col
// register tiles; row-LSE and per-wave column-LSE computed from the same tile
// (fused). V is block-internal. Only cross-block traffic: the scalar lvl
// (per-type lse(lu) partials on padded lines), combined by wave 15 overlapping
// the row pass; parity double-buffer + exact-epoch match (skew < 2 proven by
// the lvl dependency chain).
__global__ __launch_bounds__(1024) void k_sink(const float* __restrict__ Ms,
    const int* __restrict__ meta,
    u64* __restrict__ plD, unsigned* __restrict__ plE,
    float* __restrict__ luF, float* __restrict__ VF,
    int k, float l2tm) {
  __shared__ float V[KCAP];
  __shared__ float lu[LUMAX];
  __shared__ float cM[16][KCAP];
  __shared__ float cS[16][KCAP];
  __shared__ float lvl_sh;
  __shared__ int lvl_ep;
  __shared__ int tileCtr;
  int tid = threadIdx.x, lane = tid & 63, wv = tid >> 6;
  int t = blockIdx.x;
  int cR = meta[t];
  int s0 = meta[32 + t];
  int nt8 = (cR + 7) >> 3;
  int laneCnt = (lane < NT) ? meta[lane] : 0;  // for wave-15 poll mask

  for (int j = tid; j < k; j += 1024) V[j] = 0.f;
  if (tid == 0) { lvl_sh = 0.f; lvl_ep = 0; tileCtr = 0; }
  __syncthreads();

  for (int m = 0; m < NITER; m++) {
    int par = m & 1;
    int epoch = m + 1;
    // ---- PHASE A ----
    for (int j = lane; j < k; j += 64) { cM[wv][j] = -3.0e38f; cS[wv][j] = 0.f; }
    float lvl = 0.f;
    bool haveLvl = false;
    if (wv == 15) {
      if (m > 0) {
        int ppar = (m - 1) & 1;
        unsigned want = (unsigned)m;
        bool need = (lane < NT) && (laneCnt > 0);
        for (;;) {
          bool ok = !need ||
              (__hip_atomic_load(&plE[((size_t)ppar * NT + lane) * 16],
                                 __ATOMIC_RELAXED, __HIP_MEMORY_SCOPE_AGENT) == want);
          if (__all(ok)) break;
          __builtin_amdgcn_s_sleep(1);
        }
        u64 a = need
            ? __hip_atomic_load(&plD[((size_t)ppar * NT + lane) * 8],
                                __ATOMIC_RELAXED, __HIP_MEMORY_SCOPE_AGENT)
            : packf2(-3.0e38f, 0.f);
        float mm = plo(a), ss = phi(a);
#pragma unroll
        for (int o = 32; o; o >>= 1) {
          float mq = __shfl_xor(mm, o), sq = __shfl_xor(ss, o);
          float nm = fmaxf(mm, mq);
          ss = ss * EX2(mm - nm) + sq * EX2(mq - nm);
          mm = nm;
        }
        if (lane == 0) lvl_sh = l2tm - (mm + LG2(ss));
      }
      if (lane == 0)
        __hip_atomic_store(&lvl_ep, epoch, __ATOMIC_RELEASE, __HIP_MEMORY_SCOPE_WORKGROUP);
      lvl = lvl_sh;
      haveLvl = true;
    }
    for (;;) {
      int tile;
      if (lane == 0) tile = atomicAdd(&tileCtr, 1);
      tile = __shfl(tile, 0);
      tile -= 16 * m;  // counter is monotone across iters; rebase
      if (tile >= nt8) break;
      int r0 = tile << 3;
      int rlim = cR - r0; if (rlim > 8) rlim = 8;
      float a[8][NQ];
      for (int rr = 0; rr < 8; rr++) {
        if (rr < rlim) {
          const float* rp = Ms + (size_t)(s0 + r0 + rr) * k;
#pragma unroll
          for (int q = 0; q < NQ; q++) {
            int j = lane + (q << 6);
            a[rr][q] = (j < k) ? rp[j] : -3.0e38f;
          }
        }
      }
      float vq[NQ];
#pragma unroll
      for (int q = 0; q < NQ; q++) {
        int j = lane + (q << 6);
        vq[q] = (j < k) ? V[j] : -3.0e38f;
      }
      if (!haveLvl) {
        while (__hip_atomic_load(&lvl_ep, __ATOMIC_ACQUIRE, __HIP_MEMORY_SCOPE_WORKGROUP) < epoch)
          __builtin_amdgcn_s_sleep(1);
        lvl = lvl_sh;
        haveLvl = true;
      }
      float lur[8];
      for (int rr = 0; rr < rlim; rr++) {
        float xq[NQ];
#pragma unroll
        for (int q = 0; q < NQ; q++) xq[q] = a[rr][q] + vq[q];
        float pm = xq[0];
#pragma unroll
        for (int q = 1; q < NQ; q++) pm = fmaxf(pm, xq[q]);
#pragma unroll
        for (int o = 32; o; o >>= 1) pm = fmaxf(pm, __shfl_xor(pm, o));
        float ps = 0.f;
#pragma unroll
        for (int q = 0; q < NQ; q++) ps += EX2(xq[q] - pm);
#pragma unroll
        for (int o = 32; o; o >>= 1) ps += __shfl_xor(ps, o);
        float nm = fmaxf(pm, lvl);
        float s = ps * EX2(pm - nm) + EX2(lvl - nm);
        float l = -(nm + LG2(s));
        lur[rr] = l;
        if (lane == 0) lu[r0 + rr] = l;
      }
#pragma unroll
      for (int q = 0; q < NQ; q++) {
        int j = lane + (q << 6);
        if (j < k) {
          float cm = -3.0e38f;
          for (int rr = 0; rr < rlim; rr++) cm = fmaxf(cm, a[rr][q] + lur[rr]);
          float es = 0.f;
          for (int rr = 0; rr < rlim; rr++) es += EX2(a[rr][q] + lur[rr] - cm);
          float om = cM[wv][j], os = cS[wv][j];
          float nm2 = fmaxf(om, cm);
          cS[wv][j] = os * EX2(om - nm2) + es * EX2(cm - nm2);
          cM[wv][j] = nm2;
        }
      }
    }
    __syncthreads();
    // ---- PHASE B ----
    if (tid < k) {
      float mm = cM[0][tid], ss = cS[0][tid];
#pragma unroll
      for (int w = 1; w < 16; w++) {
        float mq = cM[w][tid], sq = cS[w][tid];
        float nm = fmaxf(mm, mq);
        ss = ss * EX2(mm - nm) + sq * EX2(mq - nm);
        mm = nm;
      }
      V[tid] = -(mm + LG2(ss));
    }
    if (wv == 15) {
      float om = -3.0e38f, os = 0.f;
      for (int r = lane; r < cR; r += 64) {
        float x = lu[r];
        float nm = fmaxf(om, x);
        os = os * EX2(om - nm) + EX2(x - nm);
        om = nm;
      }
#pragma unroll
      for (int o = 32; o; o >>= 1) {
        float mq = __shfl_xor(om, o), sq = __shfl_xor(os, o);
        float nm = fmaxf(om, mq);
        os = os * EX2(om - nm) + sq * EX2(mq - nm);
        om = nm;
      }
      if (lane == 0)
        __hip_atomic_store(&plD[((size_t)par * NT + t) * 8], packf2(om, os),
                           __ATOMIC_RELAXED, __HIP_MEMORY_SCOPE_AGENT);
      __builtin_amdgcn_s_waitcnt(0);  // data globally visible before epoch
      if (lane == 0)
        __hip_atomic_store(&plE[((size_t)par * NT + t) * 16], (unsigned)epoch,
                           __ATOMIC_RELAXED, __HIP_MEMORY_SCOPE_AGENT);
    }
    if (tid == 1023) { /* rebase happens via tile-=16*m; counter keeps rolling */ }
    __syncthreads();
    // restore invariant: counter must equal 16*(m+1) for next iter's rebase;
    // lanes grabbed extra up to 16 per wave -> clamp by rewrite
    if (tid == 0) tileCtr = 16 * (m + 1);
    __syncthreads();
  }
  for (int r = tid; r < cR; r += 1024) luF[s0 + r] = lu[r];
  for (int j = tid; j < k; j += 1024) VF[(size_t)t * k + j] = V[j];
}

// epilogue (base-2): logits = ln(exp2(M+lu+V)+1e-8); T row scatter into j*17+t
__global__ __launch_bounds__(256) void k_epi(const float* __restrict__ Ms,
    const float* __restrict__ luF, const float* __restrict__ VF,
    const int* __restrict__ perm, const int* __restrict__ tys,
    float* __restrict__ out, int n, int k) {
  __shared__ float vals[KCAP];
  int r = blockIdx.x;
  int i = perm[r], t = tys[r];
  float lu = luF[r];
  const float* Mrow = Ms + (size_t)r * k;
  const float* Vrow = VF + (size_t)t * k;
  for (int j = threadIdx.x; j < k; j += 256) vals[j] = EX2(Mrow[j] + lu + Vrow[j]);
  __syncthreads();
  float* lg = out + (size_t)i * k;
  for (int j = threadIdx.x; j < k; j += 256)
    lg[j] = LG2(vals[j] + 1e-8f) * 0.6931471805599453f;
  int ns = k * NT;
  float* Trow = out + (size_t)n * k + (size_t)i * ns;
  if ((ns & 3) == 0 && (((size_t)n * k) & 3) == 0) {
    int n4 = ns >> 2;
    for (int g4 = threadIdx.x; g4 < n4; g4 += 256) {
      int o0 = g4 << 2;
      float v[4] = {0.f, 0.f, 0.f, 0.f};
#pragma unroll
      for (int s = 0; s < 4; s++) {
        int o = o0 + s;
        int j = o / NT;
        int tt = o - j * NT;
        if (tt == t) v[s] = vals[j];
      }
      *(float4*)(Trow + o0) = make_float4(v[0], v[1], v[2], v[3]);
    }
  } else {
    for (int o = threadIdx.x; o < ns; o += 256) {
      int j = o / NT;
      int tt = o - j * NT;
      Trow[o] = (tt == t) ? vals[j] : 0.f;
    }
  }
}

extern "C" void kernel_launch(void* const* d_in, const int* in_sizes, int n_in,
                              void* d_out, int out_size, void* d_ws, size_t ws_size,
                              hipStream_t stream) {
  const float* emb = (const float*)d_in[0];
  const float* W1  = (const float*)d_in[1];
  const float* b1  = (const float*)d_in[2];
  const float* P   = (const float*)d_in[3];
  const int*   jt  = (const int*)d_in[4];
  (void)n_in; (void)ws_size;

  const int n = in_sizes[4];
  const int H = in_sizes[2];
  const int D = in_sizes[1] / H;
  const int k = out_size / (n * (NT + 1));
  const int nslots = k * NT;
  const float tm_last = (float)((n - nslots) > 1 ? (n - nslots) : 1);
  const float l2tm = log2f(tm_last);

  char* w = (char*)d_ws;
  size_t off = 0;
  auto take = [&](size_t bytes) -> char* {
    char* p = w + off;
    off = (off + bytes + 255) & ~(size_t)255;
    return p;
  };
  int*      meta = (int*)take(4096);
  int*      perm = (int*)take((size_t)n * 4);
  int*      tys  = (int*)take((size_t)n * 4);
  float*    h    = (float*)take((size_t)n * H * 4);
  float*    hsq  = (float*)take((size_t)n * 4);
  float*    psq  = (float*)take((size_t)k * 4);
  float*    Ms   = (float*)take((size_t)n * k * 4);
  u64*      plD  = (u64*)take((size_t)2 * NT * 64);
  unsigned* plE  = (unsigned*)take((size_t)2 * NT * 64);
  float*    luF  = (float*)take((size_t)n * 4);
  float*    VF   = (float*)take((size_t)NT * k * 4);

  (void)hipMemsetAsync(meta, 0, 4096, stream);
  (void)hipMemsetAsync(plE, 0, (size_t)2 * NT * 64, stream);
  k_hist<<<(n + 255) / 256, 256, 0, stream>>>(jt, n, meta);
  k_scatter<<<(n + 255) / 256, 256, 0, stream>>>(jt, n, meta, perm, tys);
  k_hgemm<<<dim3(n / 64, H / 64), dim3(256), 0, stream>>>(emb, W1, b1, h, n, D, H);
  k_norms<<<(n + k + 3) / 4, 256, 0, stream>>>(h, P, hsq, psq, n, H, k);
  k_msort<<<dim3(n / 64, (k + 63) / 64), dim3(256), 0, stream>>>(h, P, hsq, psq, perm, Ms, n, H, k);
  k_sink<<<NT, 1024, 0, stream>>>(Ms, meta, plD, plE, luF, VF, k, l2tm);
  k_epi<<<n, 256, 0, stream>>>(Ms, luF, VF, perm, tys, (float*)d_out, n, k);
}

// Round 8
// 936.947 us; speedup vs baseline: 2.5758x; 2.5758x over previous
//
#include <hip/hip_runtime.h>
#include <math.h>

#define NT 17
#define KCAP 300
#define NITER 30
#define NQ 5        // ceil(KCAP/64)
#define LUMAX 1024  // max rows per type
// -1/tau * log2(e): sinkhorn runs in base-2 log domain
#define MSCALE2 28.853900817779268f

typedef unsigned long long u64;

#define EX2(x) __builtin_amdgcn_exp2f(x)
#define LG2(x) __builtin_amdgcn_logf(x)

// ---- meta layout (ints at ws start, zeroed each launch) ----
// [0..16]   typeCount
// [32..48]  typeOff
// [64..95]  scatterCnt
// [96]      doneFlag

__device__ inline u64 packf2(float m, float s) {
  return ((u64)__float_as_uint(s) << 32) | (u64)__float_as_uint(m);
}
__device__ inline float plo(u64 p) { return __uint_as_float((unsigned)p); }
__device__ inline float phi(u64 p) { return __uint_as_float((unsigned)(p >> 32)); }

__device__ inline float selu_f(float x) {
  const float scale = 1.0507009873554804934193349852946f;
  const float alpha = 1.6732632423543772848170429916717f;
  return x > 0.f ? scale * x : scale * alpha * (EX2(x * 1.4426950408889634f) - 1.f);
}

__global__ void k_hist(const int* __restrict__ jt, int n, int* meta) {
  int i = blockIdx.x * 256 + threadIdx.x;
  if (i < n) atomicAdd(&meta[jt[i]], 1);
  __syncthreads();
  if (threadIdx.x == 0) {
    __threadfence();
    int d = atomicAdd(&meta[96], 1);
    if (d == (int)gridDim.x - 1) {
      int off = 0;
      for (int t = 0; t < NT; t++) {
        int c = __hip_atomic_load(&meta[t], __ATOMIC_RELAXED, __HIP_MEMORY_SCOPE_AGENT);
        meta[32 + t] = off;
        off += c;
      }
      __threadfence();
    }
  }
}

__global__ void k_scatter(const int* __restrict__ jt, int n, int* meta,
                          int* __restrict__ perm, int* __restrict__ tys) {
  int i = blockIdx.x * 256 + threadIdx.x;
  if (i < n) {
    int t = jt[i];
    int pos = meta[32 + t] + atomicAdd(&meta[64 + t], 1);
    perm[pos] = i;
    tys[pos] = t;
  }
}

// h = selu(emb @ W1 + b1)   (n x D) @ (D x H)
__global__ __launch_bounds__(256) void k_hgemm(const float* __restrict__ A,
    const float* __restrict__ B, const float* __restrict__ bias,
    float* __restrict__ C, int n, int D, int H) {
  __shared__ __align__(16) float As[16][68];
  __shared__ __align__(16) float Bs[16][68];
  int tid = threadIdx.x;
  int i0 = blockIdx.x * 64, j0 = blockIdx.y * 64;
  int tx = tid & 15, ty = tid >> 4;
  int aI = tid & 63, aK = (tid >> 6) << 2;
  int bJ = (tid & 15) << 2, bK = tid >> 4;
  float acc[4][4] = {};
  for (int k0 = 0; k0 < D; k0 += 16) {
    float4 av = *(const float4*)(A + (size_t)(i0 + aI) * D + k0 + aK);
    float4 bv = *(const float4*)(B + (size_t)(k0 + bK) * H + j0 + bJ);
    __syncthreads();
    As[aK + 0][aI] = av.x; As[aK + 1][aI] = av.y; As[aK + 2][aI] = av.z; As[aK + 3][aI] = av.w;
    *(float4*)(&Bs[bK][bJ]) = bv;
    __syncthreads();
#pragma unroll
    for (int kk = 0; kk < 16; kk++) {
      float4 a4 = *(float4*)(&As[kk][ty << 2]);
      float4 b4 = *(float4*)(&Bs[kk][tx << 2]);
      float aa[4] = {a4.x, a4.y, a4.z, a4.w};
      float bb[4] = {b4.x, b4.y, b4.z, b4.w};
#pragma unroll
      for (int p = 0; p < 4; p++)
#pragma unroll
        for (int q = 0; q < 4; q++)
          acc[p][q] = fmaf(aa[p], bb[q], acc[p][q]);
    }
  }
#pragma unroll
  for (int p = 0; p < 4; p++) {
    int i = i0 + (ty << 2) + p;
    float o[4];
#pragma unroll
    for (int q = 0; q < 4; q++) {
      int j = j0 + (tx << 2) + q;
      o[q] = selu_f(acc[p][q] + bias[j]);
    }
    *(float4*)(C + (size_t)i * H + j0 + (tx << 2)) = make_float4(o[0], o[1], o[2], o[3]);
  }
}

// row norms of h (n rows) and prototypes (k rows)
__global__ __launch_bounds__(256) void k_norms(const float* __restrict__ h,
    const float* __restrict__ P, float* __restrict__ hsq, float* __restrict__ psq,
    int n, int H, int k) {
  int wv = threadIdx.x >> 6, lane = threadIdx.x & 63;
  int idx = blockIdx.x * 4 + wv;
  const float* src; float* dst;
  if (idx < n) { src = h + (size_t)idx * H; dst = hsq + idx; }
  else if (idx < n + k) { int j = idx - n; src = P + (size_t)j * H; dst = psq + j; }
  else return;
  float s = 0.f;
  for (int d = lane * 4; d < H; d += 256) {
    float4 v = *(const float4*)(src + d);
    s += v.x * v.x + v.y * v.y + v.z * v.z + v.w * v.w;
  }
#pragma unroll
  for (int o = 32; o; o >>= 1) s += __shfl_xor(s, o);
  if (lane == 0) *dst = s;
}

// Ms[r][j] = -max(0, hsq+psq-2*dot)/tau * log2(e)  (base-2 domain), rows type-sorted
__global__ __launch_bounds__(256) void k_msort(const float* __restrict__ h,
    const float* __restrict__ P, const float* __restrict__ hsq,
    const float* __restrict__ psq, const int* __restrict__ perm,
    float* __restrict__ Ms, int n, int H, int k) {
  __shared__ __align__(16) float As[16][68];
  __shared__ __align__(16) float Bs[16][68];
  __shared__ int gIdx[64];
  int tid = threadIdx.x;
  int i0 = blockIdx.x * 64, j0 = blockIdx.y * 64;
  if (tid < 64) gIdx[tid] = perm[i0 + tid];
  __syncthreads();
  int tx = tid & 15, ty = tid >> 4;
  int aI = tid & 63, aK = (tid >> 6) << 2;
  int gA = gIdx[aI];
  bool bok = (j0 + aI) < k;
  const float* bRow = P + (size_t)(j0 + (bok ? aI : 0)) * H;
  float acc[4][4] = {};
  for (int k0 = 0; k0 < H; k0 += 16) {
    float4 av = *(const float4*)(h + (size_t)gA * H + k0 + aK);
    float4 bv = *(const float4*)(bRow + k0 + aK);
    __syncthreads();
    As[aK + 0][aI] = av.x; As[aK + 1][aI] = av.y; As[aK + 2][aI] = av.z; As[aK + 3][aI] = av.w;
    Bs[aK + 0][aI] = bv.x; Bs[aK + 1][aI] = bv.y; Bs[aK + 2][aI] = bv.z; Bs[aK + 3][aI] = bv.w;
    __syncthreads();
#pragma unroll
    for (int kk = 0; kk < 16; kk++) {
      float4 a4 = *(float4*)(&As[kk][ty << 2]);
      float4 b4 = *(float4*)(&Bs[kk][tx << 2]);
      float aa[4] = {a4.x, a4.y, a4.z, a4.w};
      float bb[4] = {b4.x, b4.y, b4.z, b4.w};
#pragma unroll
      for (int p = 0; p < 4; p++)
#pragma unroll
        for (int q = 0; q < 4; q++)
          acc[p][q] = fmaf(aa[p], bb[q], acc[p][q]);
    }
  }
#pragma unroll
  for (int p = 0; p < 4; p++) {
    int rr = (ty << 2) + p;
    int r = i0 + rr;
    float hq = hsq[gIdx[rr]];
#pragma unroll
    for (int q = 0; q < 4; q++) {
      int j = j0 + (tx << 2) + q;
      if (j < k) {
        float d2 = hq + psq[j] - 2.f * acc[p][q];
        d2 = fmaxf(d2, 0.f);
        Ms[(size_t)r * k + j] = -d2 * MSCALE2;
      }
    }
  }
}

// Persistent Sinkhorn, base-2 log domain. ONE TYPE PER BLOCK (17 blocks x 1024).
// M slab streamed from L2 each iteration into fully-unrolled 8x5 register
// tiles (compile-time bounds + predication -> no scratch spill). Static wave
// partition of tiles. Only cross-block traffic: scalar lvl partials (wave 15,
// overlapped with the row pass; parity + exact-epoch, skew<2 proven).
__global__ __launch_bounds__(1024) void k_sink(const float* __restrict__ Ms,
    const int* __restrict__ meta,
    u64* __restrict__ plD, unsigned* __restrict__ plE,
    float* __restrict__ luF, float* __restrict__ VF,
    int k, float l2tm) {
  __shared__ float V[KCAP];
  __shared__ float lu[LUMAX];
  __shared__ float cM[16][KCAP];
  __shared__ float cS[16][KCAP];
  __shared__ float lvl_sh;
  __shared__ int lvl_ep;
  int tid = threadIdx.x, lane = tid & 63, wv = tid >> 6;
  int t = blockIdx.x;
  int cR = meta[t];
  int s0 = meta[32 + t];
  int nt8 = (cR + 7) >> 3;
  int laneCnt = (lane < NT) ? meta[lane] : 0;  // for wave-15 poll mask

  for (int j = tid; j < k; j += 1024) V[j] = 0.f;
  if (tid == 0) { lvl_sh = 0.f; lvl_ep = 0; }
  __syncthreads();

  for (int m = 0; m < NITER; m++) {
    int par = m & 1;
    int epoch = m + 1;
    // ---- PHASE A: fused row-LSE + per-wave col-LSE over register tiles ----
    for (int j = lane; j < k; j += 64) { cM[wv][j] = -3.0e38f; cS[wv][j] = 0.f; }
    float lvl = 0.f;
    bool haveLvl = false;
    if (wv == 15) {
      if (m > 0) {
        int ppar = (m - 1) & 1;
        unsigned want = (unsigned)m;
        bool need = (lane < NT) && (laneCnt > 0);
        for (;;) {
          bool ok = !need ||
              (__hip_atomic_load(&plE[((size_t)ppar * NT + lane) * 16],
                                 __ATOMIC_RELAXED, __HIP_MEMORY_SCOPE_AGENT) == want);
          if (__all(ok)) break;
          __builtin_amdgcn_s_sleep(1);
        }
        u64 a = need
            ? __hip_atomic_load(&plD[((size_t)ppar * NT + lane) * 8],
                                __ATOMIC_RELAXED, __HIP_MEMORY_SCOPE_AGENT)
            : packf2(-3.0e38f, 0.f);
        float mm = plo(a), ss = phi(a);
#pragma unroll
        for (int o = 32; o; o >>= 1) {
          float mq = __shfl_xor(mm, o), sq = __shfl_xor(ss, o);
          float nm = fmaxf(mm, mq);
          ss = ss * EX2(mm - nm) + sq * EX2(mq - nm);
          mm = nm;
        }
        if (lane == 0) lvl_sh = l2tm - (mm + LG2(ss));
      }
      if (lane == 0)
        __hip_atomic_store(&lvl_ep, epoch, __ATOMIC_RELEASE, __HIP_MEMORY_SCOPE_WORKGROUP);
      lvl = lvl_sh;
      haveLvl = true;
    }
    for (int tile = wv; tile < nt8; tile += 16) {
      int r0 = tile << 3;
      int rlim = cR - r0; if (rlim > 8) rlim = 8;
      const float* base = Ms + (size_t)(s0 + r0) * k;
      float a[8][NQ];
#pragma unroll
      for (int rr = 0; rr < 8; rr++) {
        const float* rp = base + (size_t)(rr < rlim ? rr : 0) * k;
#pragma unroll
        for (int q = 0; q < NQ; q++) {
          int j = lane + (q << 6);
          a[rr][q] = (j < k) ? rp[j] : -3.0e38f;
        }
      }
      float vq[NQ];
#pragma unroll
      for (int q = 0; q < NQ; q++) {
        int j = lane + (q << 6);
        vq[q] = (j < k) ? V[j] : -3.0e38f;
      }
      if (!haveLvl) {
        while (__hip_atomic_load(&lvl_ep, __ATOMIC_ACQUIRE, __HIP_MEMORY_SCOPE_WORKGROUP) < epoch)
          __builtin_amdgcn_s_sleep(1);
        lvl = lvl_sh;
        haveLvl = true;
      }
      float lur[8];
#pragma unroll
      for (int rr = 0; rr < 8; rr++) {
        float xq[NQ];
#pragma unroll
        for (int q = 0; q < NQ; q++) xq[q] = a[rr][q] + vq[q];
        float pm = xq[0];
#pragma unroll
        for (int q = 1; q < NQ; q++) pm = fmaxf(pm, xq[q]);
#pragma unroll
        for (int o = 32; o; o >>= 1) pm = fmaxf(pm, __shfl_xor(pm, o));
        float ps = 0.f;
#pragma unroll
        for (int q = 0; q < NQ; q++) ps += EX2(xq[q] - pm);
#pragma unroll
        for (int o = 32; o; o >>= 1) ps += __shfl_xor(ps, o);
        float nm = fmaxf(pm, lvl);
        float s = ps * EX2(pm - nm) + EX2(lvl - nm);
        float l = -(nm + LG2(s));
        bool valid = (rr < rlim);
        lur[rr] = valid ? l : -3.0e38f;  // masked rows contribute exp2(-huge)=0
        if (lane == 0 && valid) lu[r0 + rr] = l;
      }
#pragma unroll
      for (int q = 0; q < NQ; q++) {
        int j = lane + (q << 6);
        if (j < k) {
          float x0 = a[0][q] + lur[0];
          float cm = x0;
#pragma unroll
          for (int rr = 1; rr < 8; rr++) cm = fmaxf(cm, a[rr][q] + lur[rr]);
          float es = 0.f;
#pragma unroll
          for (int rr = 0; rr < 8; rr++) es += EX2(a[rr][q] + lur[rr] - cm);
          float om = cM[wv][j], os = cS[wv][j];
          float nm2 = fmaxf(om, cm);
          cS[wv][j] = os * EX2(om - nm2) + es * EX2(cm - nm2);
          cM[wv][j] = nm2;
        }
      }
    }
    __syncthreads();
    // ---- PHASE B: 16-way col merge -> V ; wave 15: lse(lu) -> pl publish ----
    if (tid < k) {
      float mm = cM[0][tid], ss = cS[0][tid];
#pragma unroll
      for (int w = 1; w < 16; w++) {
        float mq = cM[w][tid], sq = cS[w][tid];
        float nm = fmaxf(mm, mq);
        ss = ss * EX2(mm - nm) + sq * EX2(mq - nm);
        mm = nm;
      }
      V[tid] = -(mm + LG2(ss));
    }
    if (wv == 15) {
      float om = -3.0e38f, os = 0.f;
      for (int r = lane; r < cR; r += 64) {
        float x = lu[r];
        float nm = fmaxf(om, x);
        os = os * EX2(om - nm) + EX2(x - nm);
        om = nm;
      }
#pragma unroll
      for (int o = 32; o; o >>= 1) {
        float mq = __shfl_xor(om, o), sq = __shfl_xor(os, o);
        float nm = fmaxf(om, mq);
        os = os * EX2(om - nm) + sq * EX2(mq - nm);
        om = nm;
      }
      if (lane == 0)
        __hip_atomic_store(&plD[((size_t)par * NT + t) * 8], packf2(om, os),
                           __ATOMIC_RELAXED, __HIP_MEMORY_SCOPE_AGENT);
      __builtin_amdgcn_s_waitcnt(0);  // data globally visible before epoch
      if (lane == 0)
        __hip_atomic_store(&plE[((size_t)par * NT + t) * 16], (unsigned)epoch,
                           __ATOMIC_RELAXED, __HIP_MEMORY_SCOPE_AGENT);
    }
    __syncthreads();
  }
  for (int r = tid; r < cR; r += 1024) luF[s0 + r] = lu[r];
  for (int j = tid; j < k; j += 1024) VF[(size_t)t * k + j] = V[j];
}

// epilogue (base-2): logits = ln(exp2(M+lu+V)+1e-8); T row scatter into j*17+t
__global__ __launch_bounds__(256) void k_epi(const float* __restrict__ Ms,
    const float* __restrict__ luF, const float* __restrict__ VF,
    const int* __restrict__ perm, const int* __restrict__ tys,
    float* __restrict__ out, int n, int k) {
  __shared__ float vals[KCAP];
  int r = blockIdx.x;
  int i = perm[r], t = tys[r];
  float lu = luF[r];
  const float* Mrow = Ms + (size_t)r * k;
  const float* Vrow = VF + (size_t)t * k;
  for (int j = threadIdx.x; j < k; j += 256) vals[j] = EX2(Mrow[j] + lu + Vrow[j]);
  __syncthreads();
  float* lg = out + (size_t)i * k;
  for (int j = threadIdx.x; j < k; j += 256)
    lg[j] = LG2(vals[j] + 1e-8f) * 0.6931471805599453f;
  int ns = k * NT;
  float* Trow = out + (size_t)n * k + (size_t)i * ns;
  if ((ns & 3) == 0 && (((size_t)n * k) & 3) == 0) {
    int n4 = ns >> 2;
    for (int g4 = threadIdx.x; g4 < n4; g4 += 256) {
      int o0 = g4 << 2;
      float v[4] = {0.f, 0.f, 0.f, 0.f};
#pragma unroll
      for (int s = 0; s < 4; s++) {
        int o = o0 + s;
        int j = o / NT;
        int tt = o - j * NT;
        if (tt == t) v[s] = vals[j];
      }
      *(float4*)(Trow + o0) = make_float4(v[0], v[1], v[2], v[3]);
    }
  } else {
    for (int o = threadIdx.x; o < ns; o += 256) {
      int j = o / NT;
      int tt = o - j * NT;
      Trow[o] = (tt == t) ? vals[j] : 0.f;
    }
  }
}

extern "C" void kernel_launch(void* const* d_in, const int* in_sizes, int n_in,
                              void* d_out, int out_size, void* d_ws, size_t ws_size,
                              hipStream_t stream) {
  const float* emb = (const float*)d_in[0];
  const float* W1  = (const float*)d_in[1];
  const float* b1  = (const float*)d_in[2];
  const float* P   = (const float*)d_in[3];
  const int*   jt  = (const int*)d_in[4];
  (void)n_in; (void)ws_size;

  const int n = in_sizes[4];
  const int H = in_sizes[2];
  const int D = in_sizes[1] / H;
  const int k = out_size / (n * (NT + 1));
  const int nslots = k * NT;
  const float tm_last = (float)((n - nslots) > 1 ? (n - nslots) : 1);
  const float l2tm = log2f(tm_last);

  char* w = (char*)d_ws;
  size_t off = 0;
  auto take = [&](size_t bytes) -> char* {
    char* p = w + off;
    off = (off + bytes + 255) & ~(size_t)255;
    return p;
  };
  int*      meta = (int*)take(4096);
  int*      perm = (int*)take((size_t)n * 4);
  int*      tys  = (int*)take((size_t)n * 4);
  float*    h    = (float*)take((size_t)n * H * 4);
  float*    hsq  = (float*)take((size_t)n * 4);
  float*    psq  = (float*)take((size_t)k * 4);
  float*    Ms   = (float*)take((size_t)n * k * 4);
  u64*      plD  = (u64*)take((size_t)2 * NT * 64);
  unsigned* plE  = (unsigned*)take((size_t)2 * NT * 64);
  float*    luF  = (float*)take((size_t)n * 4);
  float*    VF   = (float*)take((size_t)NT * k * 4);

  (void)hipMemsetAsync(meta, 0, 4096, stream);
  (void)hipMemsetAsync(plE, 0, (size_t)2 * NT * 64, stream);
  k_hist<<<(n + 255) / 256, 256, 0, stream>>>(jt, n, meta);
  k_scatter<<<(n + 255) / 256, 256, 0, stream>>>(jt, n, meta, perm, tys);
  k_hgemm<<<dim3(n / 64, H / 64), dim3(256), 0, stream>>>(emb, W1, b1, h, n, D, H);
  k_norms<<<(n + k + 3) / 4, 256, 0, stream>>>(h, P, hsq, psq, n, H, k);
  k_msort<<<dim3(n / 64, (k + 63) / 64), dim3(256), 0, stream>>>(h, P, hsq, psq, perm, Ms, n, H, k);
  k_sink<<<NT, 1024, 0, stream>>>(Ms, meta, plD, plE, luF, VF, k, l2tm);
  k_epi<<<n, 256, 0, stream>>>(Ms, luF, VF, perm, tys, (float*)d_out, n, k);
}

// Round 9
// 574.440 us; speedup vs baseline: 4.2013x; 1.6311x over previous
//
#include <hip/hip_runtime.h>
#include <math.h>

#define NT 17
#define KCAP 300
#define NITER 30
#define TR 4        // rows per register tile
#define LUMAX 1024  // max rows per type
// -1/tau * log2(e): B matrix is in base-2 log domain
#define MSCALE2 28.853900817779268f

typedef unsigned long long u64;

#define EX2(x) __builtin_amdgcn_exp2f(x)
#define LG2(x) __builtin_amdgcn_logf(x)
#if __has_builtin(__builtin_amdgcn_rcpf)
#define RCP(x) __builtin_amdgcn_rcpf(x)
#else
#define RCP(x) (1.0f / (x))
#endif

// ---- meta layout (ints at ws start, zeroed each launch) ----
// [0..16]   typeCount
// [32..48]  typeOff
// [64..95]  scatterCnt
// [96]      doneFlag

__device__ inline float selu_f(float x) {
  const float scale = 1.0507009873554804934193349852946f;
  const float alpha = 1.6732632423543772848170429916717f;
  return x > 0.f ? scale * x : scale * alpha * (EX2(x * 1.4426950408889634f) - 1.f);
}

__global__ void k_hist(const int* __restrict__ jt, int n, int* meta) {
  int i = blockIdx.x * 256 + threadIdx.x;
  if (i < n) atomicAdd(&meta[jt[i]], 1);
  __syncthreads();
  if (threadIdx.x == 0) {
    __threadfence();
    int d = atomicAdd(&meta[96], 1);
    if (d == (int)gridDim.x - 1) {
      int off = 0;
      for (int t = 0; t < NT; t++) {
        int c = __hip_atomic_load(&meta[t], __ATOMIC_RELAXED, __HIP_MEMORY_SCOPE_AGENT);
        meta[32 + t] = off;
        off += c;
      }
      __threadfence();
    }
  }
}

__global__ void k_scatter(const int* __restrict__ jt, int n, int* meta,
                          int* __restrict__ perm, int* __restrict__ tys) {
  int i = blockIdx.x * 256 + threadIdx.x;
  if (i < n) {
    int t = jt[i];
    int pos = meta[32 + t] + atomicAdd(&meta[64 + t], 1);
    perm[pos] = i;
    tys[pos] = t;
  }
}

// h = selu(emb @ W1 + b1)   (n x D) @ (D x H)
__global__ __launch_bounds__(256) void k_hgemm(const float* __restrict__ A,
    const float* __restrict__ B, const float* __restrict__ bias,
    float* __restrict__ C, int n, int D, int H) {
  __shared__ __align__(16) float As[16][68];
  __shared__ __align__(16) float Bs[16][68];
  int tid = threadIdx.x;
  int i0 = blockIdx.x * 64, j0 = blockIdx.y * 64;
  int tx = tid & 15, ty = tid >> 4;
  int aI = tid & 63, aK = (tid >> 6) << 2;
  int bJ = (tid & 15) << 2, bK = tid >> 4;
  float acc[4][4] = {};
  for (int k0 = 0; k0 < D; k0 += 16) {
    float4 av = *(const float4*)(A + (size_t)(i0 + aI) * D + k0 + aK);
    float4 bv = *(const float4*)(B + (size_t)(k0 + bK) * H + j0 + bJ);
    __syncthreads();
    As[aK + 0][aI] = av.x; As[aK + 1][aI] = av.y; As[aK + 2][aI] = av.z; As[aK + 3][aI] = av.w;
    *(float4*)(&Bs[bK][bJ]) = bv;
    __syncthreads();
#pragma unroll
    for (int kk = 0; kk < 16; kk++) {
      float4 a4 = *(float4*)(&As[kk][ty << 2]);
      float4 b4 = *(float4*)(&Bs[kk][tx << 2]);
      float aa[4] = {a4.x, a4.y, a4.z, a4.w};
      float bb[4] = {b4.x, b4.y, b4.z, b4.w};
#pragma unroll
      for (int p = 0; p < 4; p++)
#pragma unroll
        for (int q = 0; q < 4; q++)
          acc[p][q] = fmaf(aa[p], bb[q], acc[p][q]);
    }
  }
#pragma unroll
  for (int p = 0; p < 4; p++) {
    int i = i0 + (ty << 2) + p;
    float o[4];
#pragma unroll
    for (int q = 0; q < 4; q++) {
      int j = j0 + (tx << 2) + q;
      o[q] = selu_f(acc[p][q] + bias[j]);
    }
    *(float4*)(C + (size_t)i * H + j0 + (tx << 2)) = make_float4(o[0], o[1], o[2], o[3]);
  }
}

// row norms of h (n rows) and prototypes (k rows)
__global__ __launch_bounds__(256) void k_norms(const float* __restrict__ h,
    const float* __restrict__ P, float* __restrict__ hsq, float* __restrict__ psq,
    int n, int H, int k) {
  int wv = threadIdx.x >> 6, lane = threadIdx.x & 63;
  int idx = blockIdx.x * 4 + wv;
  const float* src; float* dst;
  if (idx < n) { src = h + (size_t)idx * H; dst = hsq + idx; }
  else if (idx < n + k) { int j = idx - n; src = P + (size_t)j * H; dst = psq + j; }
  else return;
  float s = 0.f;
  for (int d = lane * 4; d < H; d += 256) {
    float4 v = *(const float4*)(src + d);
    s += v.x * v.x + v.y * v.y + v.z * v.z + v.w * v.w;
  }
#pragma unroll
  for (int o = 32; o; o >>= 1) s += __shfl_xor(s, o);
  if (lane == 0) *dst = s;
}

// Ms[r][j] = -max(0, hsq+psq-2*dot)/tau * log2(e)  (base-2 domain), rows type-sorted
__global__ __launch_bounds__(256) void k_msort(const float* __restrict__ h,
    const float* __restrict__ P, const float* __restrict__ hsq,
    const float* __restrict__ psq, const int* __restrict__ perm,
    float* __restrict__ Ms, int n, int H, int k) {
  __shared__ __align__(16) float As[16][68];
  __shared__ __align__(16) float Bs[16][68];
  __shared__ int gIdx[64];
  int tid = threadIdx.x;
  int i0 = blockIdx.x * 64, j0 = blockIdx.y * 64;
  if (tid < 64) gIdx[tid] = perm[i0 + tid];
  __syncthreads();
  int tx = tid & 15, ty = tid >> 4;
  int aI = tid & 63, aK = (tid >> 6) << 2;
  int gA = gIdx[aI];
  bool bok = (j0 + aI) < k;
  const float* bRow = P + (size_t)(j0 + (bok ? aI : 0)) * H;
  float acc[4][4] = {};
  for (int k0 = 0; k0 < H; k0 += 16) {
    float4 av = *(const float4*)(h + (size_t)gA * H + k0 + aK);
    float4 bv = *(const float4*)(bRow + k0 + aK);
    __syncthreads();
    As[aK + 0][aI] = av.x; As[aK + 1][aI] = av.y; As[aK + 2][aI] = av.z; As[aK + 3][aI] = av.w;
    Bs[aK + 0][aI] = bv.x; Bs[aK + 1][aI] = bv.y; Bs[aK + 2][aI] = bv.z; Bs[aK + 3][aI] = bv.w;
    __syncthreads();
#pragma unroll
    for (int kk = 0; kk < 16; kk++) {
      float4 a4 = *(float4*)(&As[kk][ty << 2]);
      float4 b4 = *(float4*)(&Bs[kk][tx << 2]);
      float aa[4] = {a4.x, a4.y, a4.z, a4.w};
      float bb[4] = {b4.x, b4.y, b4.z, b4.w};
#pragma unroll
      for (int p = 0; p < 4; p++)
#pragma unroll
        for (int q = 0; q < 4; q++)
          acc[p][q] = fmaf(aa[p], bb[q], acc[p][q]);
    }
  }
#pragma unroll
  for (int p = 0; p < 4; p++) {
    int rr = (ty << 2) + p;
    int r = i0 + rr;
    float hq = hsq[gIdx[rr]];
#pragma unroll
    for (int q = 0; q < 4; q++) {
      int j = j0 + (tx << 2) + q;
      if (j < k) {
        float d2 = hq + psq[j] - 2.f * acc[p][q];
        d2 = fmaxf(d2, 0.f);
        Ms[(size_t)r * k + j] = -d2 * MSCALE2;
      }
    }
  }
}

// Persistent Sinkhorn, LINEAR domain with fixed per-column max shift.
// One type per block (17 x 1024). Prologue: c_j = colmax(B); K' = exp2(B-c_j)
// written in place. Iteration: u = rcp(K'·v~ + w); v~ = rcp(K'^T u) — 2 FMA per
// element, col accumulators in registers. Only cross-block value: Σu (linear
// sum), parity+epoch published, combined by wave 15 overlapping the row pass.
__global__ __launch_bounds__(1024) void k_sink(float* __restrict__ Ms,
    const int* __restrict__ meta,
    u64* __restrict__ plD, unsigned* __restrict__ plE,
    float* __restrict__ uF, float* __restrict__ vF,
    int k, float tm_last) {
  __shared__ __align__(16) float V[KCAP];      // v~ (and c_j during prologue)
  __shared__ __align__(16) float WP[16][304];  // per-wave partials
  __shared__ float uarr[LUMAX];
  __shared__ float SU[16];
  __shared__ float w_sh;
  __shared__ int lvl_ep;
  int tid = threadIdx.x, lane = tid & 63, wv = tid >> 6;
  int t = blockIdx.x;
  int cR = meta[t];
  int s0 = meta[32 + t];
  int nt = (cR + TR - 1) / TR;
  int laneCnt = (lane < NT) ? meta[lane] : 0;
  bool l2v = lane < 11;  // k=300 -> 75 float4/row: lanes 0..63 (q0) + 0..10 (q1)

  // ---- prologue: column max, then K' = exp2(B - c_j) in place ----
  {
    float4 cm0 = make_float4(-3e38f, -3e38f, -3e38f, -3e38f);
    float4 cm1 = cm0;
    for (int tile = wv; tile < nt; tile += 16) {
      int r0 = tile * TR;
#pragma unroll
      for (int rr = 0; rr < TR; rr++) {
        int rc = (r0 + rr < cR) ? (r0 + rr) : r0;
        const float4* rp = (const float4*)(Ms + (size_t)(s0 + rc) * k);
        float4 a0 = rp[lane];
        cm0.x = fmaxf(cm0.x, a0.x); cm0.y = fmaxf(cm0.y, a0.y);
        cm0.z = fmaxf(cm0.z, a0.z); cm0.w = fmaxf(cm0.w, a0.w);
        if (l2v) {
          float4 a1 = rp[lane + 64];
          cm1.x = fmaxf(cm1.x, a1.x); cm1.y = fmaxf(cm1.y, a1.y);
          cm1.z = fmaxf(cm1.z, a1.z); cm1.w = fmaxf(cm1.w, a1.w);
        }
      }
    }
    *(float4*)&WP[wv][4 * lane] = cm0;
    if (l2v) *(float4*)&WP[wv][4 * (lane + 64)] = cm1;
    __syncthreads();
    if (tid < k) {
      float c = WP[0][tid];
#pragma unroll
      for (int q = 1; q < 16; q++) c = fmaxf(c, WP[q][tid]);
      V[tid] = c;
    }
    __syncthreads();
    float4 c0 = *(const float4*)&V[4 * lane];
    float4 c1 = l2v ? *(const float4*)&V[4 * (lane + 64)] : c0;
    for (int tile = wv; tile < nt; tile += 16) {
      int r0 = tile * TR;
#pragma unroll
      for (int rr = 0; rr < TR; rr++) {
        int r = r0 + rr;
        if (r < cR) {
          float4* rp = (float4*)(Ms + (size_t)(s0 + r) * k);
          float4 a0 = rp[lane];
          a0.x = EX2(a0.x - c0.x); a0.y = EX2(a0.y - c0.y);
          a0.z = EX2(a0.z - c0.z); a0.w = EX2(a0.w - c0.w);
          rp[lane] = a0;
          if (l2v) {
            float4 a1 = rp[lane + 64];
            a1.x = EX2(a1.x - c1.x); a1.y = EX2(a1.y - c1.y);
            a1.z = EX2(a1.z - c1.z); a1.w = EX2(a1.w - c1.w);
            rp[lane + 64] = a1;
          }
        }
      }
    }
  }
  __syncthreads();
  if (tid < k) V[tid] = 0.f;  // v~ init (exp-underflowed 2^{c_j}·1 -> exactly 0)
  if (tid == 0) { w_sh = 1.f; lvl_ep = 0; }
  __syncthreads();

  for (int m = 0; m < NITER; m++) {
    int par = m & 1;
    int epoch = m + 1;
    if (wv == 15) {
      if (m > 0) {
        int ppar = (m - 1) & 1;
        unsigned want = (unsigned)m;
        bool need = (lane < NT) && (laneCnt > 0);
        for (;;) {
          bool ok = !need ||
              (__hip_atomic_load(&plE[((size_t)ppar * NT + lane) * 16],
                                 __ATOMIC_RELAXED, __HIP_MEMORY_SCOPE_AGENT) == want);
          if (__all(ok)) break;
          __builtin_amdgcn_s_sleep(1);
        }
        u64 a = need
            ? __hip_atomic_load(&plD[((size_t)ppar * NT + lane) * 8],
                                __ATOMIC_RELAXED, __HIP_MEMORY_SCOPE_AGENT)
            : 0ull;
        float s = need ? __uint_as_float((unsigned)a) : 0.f;
#pragma unroll
        for (int o = 32; o; o >>= 1) s += __shfl_xor(s, o);
        if (lane == 0) w_sh = tm_last / s;
      }
      if (lane == 0)
        __hip_atomic_store(&lvl_ep, epoch, __ATOMIC_RELEASE, __HIP_MEMORY_SCOPE_WORKGROUP);
    }
    float w = 0.f;
    bool haveW = (wv == 15);
    if (haveW) w = w_sh;
    float su = 0.f;
    float4 acc0 = make_float4(0.f, 0.f, 0.f, 0.f);
    float4 acc1 = acc0;
    for (int tile = wv; tile < nt; tile += 16) {
      int r0 = tile * TR;
      float4 a[TR][2];
#pragma unroll
      for (int rr = 0; rr < TR; rr++) {
        int rc = (r0 + rr < cR) ? (r0 + rr) : r0;
        const float4* rp = (const float4*)(Ms + (size_t)(s0 + rc) * k);
        a[rr][0] = rp[lane];
        a[rr][1] = l2v ? rp[lane + 64] : make_float4(0.f, 0.f, 0.f, 0.f);
      }
      float4 v0 = *(const float4*)&V[4 * lane];
      float4 v1 = l2v ? *(const float4*)&V[4 * (lane + 64)] : make_float4(0.f, 0.f, 0.f, 0.f);
      float rs[TR];
#pragma unroll
      for (int rr = 0; rr < TR; rr++) {
        float s = a[rr][0].x * v0.x + a[rr][0].y * v0.y +
                  a[rr][0].z * v0.z + a[rr][0].w * v0.w +
                  a[rr][1].x * v1.x + a[rr][1].y * v1.y +
                  a[rr][1].z * v1.z + a[rr][1].w * v1.w;
        rs[rr] = s;
      }
#pragma unroll
      for (int o = 32; o; o >>= 1) {
#pragma unroll
        for (int rr = 0; rr < TR; rr++) rs[rr] += __shfl_xor(rs[rr], o);
      }
      if (!haveW) {
        while (__hip_atomic_load(&lvl_ep, __ATOMIC_ACQUIRE, __HIP_MEMORY_SCOPE_WORKGROUP) < epoch)
          __builtin_amdgcn_s_sleep(1);
        w = w_sh;
        haveW = true;
      }
      float uu[TR];
#pragma unroll
      for (int rr = 0; rr < TR; rr++) {
        bool valid = (r0 + rr < cR);
        float u = RCP(rs[rr] + w);
        uu[rr] = valid ? u : 0.f;
        su += uu[rr];
        if (lane == 0 && valid) uarr[r0 + rr] = u;
      }
#pragma unroll
      for (int rr = 0; rr < TR; rr++) {
        acc0.x += a[rr][0].x * uu[rr]; acc0.y += a[rr][0].y * uu[rr];
        acc0.z += a[rr][0].z * uu[rr]; acc0.w += a[rr][0].w * uu[rr];
        acc1.x += a[rr][1].x * uu[rr]; acc1.y += a[rr][1].y * uu[rr];
        acc1.z += a[rr][1].z * uu[rr]; acc1.w += a[rr][1].w * uu[rr];
      }
    }
    *(float4*)&WP[wv][4 * lane] = acc0;
    if (l2v) *(float4*)&WP[wv][4 * (lane + 64)] = acc1;
    if (lane == 0) SU[wv] = su;
    __syncthreads();
    if (tid < k) {
      float s = WP[0][tid];
#pragma unroll
      for (int q = 1; q < 16; q++) s += WP[q][tid];
      V[tid] = RCP(s);
    }
    if (wv == 15) {
      float sp = (lane < 16) ? SU[lane] : 0.f;
#pragma unroll
      for (int o = 32; o; o >>= 1) sp += __shfl_xor(sp, o);
      if (lane == 0)
        __hip_atomic_store(&plD[((size_t)par * NT + t) * 8],
                           (u64)__float_as_uint(sp),
                           __ATOMIC_RELAXED, __HIP_MEMORY_SCOPE_AGENT);
      __builtin_amdgcn_s_waitcnt(0);  // data globally visible before epoch
      if (lane == 0)
        __hip_atomic_store(&plE[((size_t)par * NT + t) * 16], (unsigned)epoch,
                           __ATOMIC_RELAXED, __HIP_MEMORY_SCOPE_AGENT);
    }
    __syncthreads();
  }
  for (int r = tid; r < cR; r += 1024) uF[s0 + r] = uarr[r];
  for (int j = tid; j < k; j += 1024) vF[(size_t)t * k + j] = V[j];
}

// epilogue (linear): T_rj = K'_rj·u_r·v~_j; logits = ln(T + 1e-8); scatter T
__global__ __launch_bounds__(256) void k_epi(const float* __restrict__ Ms,
    const float* __restrict__ uF, const float* __restrict__ vF,
    const int* __restrict__ perm, const int* __restrict__ tys,
    float* __restrict__ out, int n, int k) {
  __shared__ float vals[KCAP];
  int r = blockIdx.x;
  int i = perm[r], t = tys[r];
  float u = uF[r];
  const float* Krow = Ms + (size_t)r * k;
  const float* Vrow = vF + (size_t)t * k;
  for (int j = threadIdx.x; j < k; j += 256) vals[j] = Krow[j] * u * Vrow[j];
  __syncthreads();
  float* lg = out + (size_t)i * k;
  for (int j = threadIdx.x; j < k; j += 256)
    lg[j] = LG2(vals[j] + 1e-8f) * 0.6931471805599453f;
  int ns = k * NT;
  float* Trow = out + (size_t)n * k + (size_t)i * ns;
  if ((ns & 3) == 0 && (((size_t)n * k) & 3) == 0) {
    int n4 = ns >> 2;
    for (int g4 = threadIdx.x; g4 < n4; g4 += 256) {
      int o0 = g4 << 2;
      float v[4] = {0.f, 0.f, 0.f, 0.f};
#pragma unroll
      for (int s = 0; s < 4; s++) {
        int o = o0 + s;
        int j = o / NT;
        int tt = o - j * NT;
        if (tt == t) v[s] = vals[j];
      }
      *(float4*)(Trow + o0) = make_float4(v[0], v[1], v[2], v[3]);
    }
  } else {
    for (int o = threadIdx.x; o < ns; o += 256) {
      int j = o / NT;
      int tt = o - j * NT;
      Trow[o] = (tt == t) ? vals[j] : 0.f;
    }
  }
}

extern "C" void kernel_launch(void* const* d_in, const int* in_sizes, int n_in,
                              void* d_out, int out_size, void* d_ws, size_t ws_size,
                              hipStream_t stream) {
  const float* emb = (const float*)d_in[0];
  const float* W1  = (const float*)d_in[1];
  const float* b1  = (const float*)d_in[2];
  const float* P   = (const float*)d_in[3];
  const int*   jt  = (const int*)d_in[4];
  (void)n_in; (void)ws_size;

  const int n = in_sizes[4];
  const int H = in_sizes[2];
  const int D = in_sizes[1] / H;
  const int k = out_size / (n * (NT + 1));
  const int nslots = k * NT;
  const float tm_last = (float)((n - nslots) > 1 ? (n - nslots) : 1);

  char* w = (char*)d_ws;
  size_t off = 0;
  auto take = [&](size_t bytes) -> char* {
    char* p = w + off;
    off = (off + bytes + 255) & ~(size_t)255;
    return p;
  };
  int*      meta = (int*)take(4096);
  int*      perm = (int*)take((size_t)n * 4);
  int*      tys  = (int*)take((size_t)n * 4);
  float*    h    = (float*)take((size_t)n * H * 4);
  float*    hsq  = (float*)take((size_t)n * 4);
  float*    psq  = (float*)take((size_t)k * 4);
  float*    Ms   = (float*)take((size_t)n * k * 4);
  u64*      plD  = (u64*)take((size_t)2 * NT * 64);
  unsigned* plE  = (unsigned*)take((size_t)2 * NT * 64);
  float*    uF   = (float*)take((size_t)n * 4);
  float*    vF   = (float*)take((size_t)NT * k * 4);

  (void)hipMemsetAsync(meta, 0, 4096, stream);
  (void)hipMemsetAsync(plE, 0, (size_t)2 * NT * 64, stream);
  k_hist<<<(n + 255) / 256, 256, 0, stream>>>(jt, n, meta);
  k_scatter<<<(n + 255) / 256, 256, 0, stream>>>(jt, n, meta, perm, tys);
  k_hgemm<<<dim3(n / 64, H / 64), dim3(256), 0, stream>>>(emb, W1, b1, h, n, D, H);
  k_norms<<<(n + k + 3) / 4, 256, 0, stream>>>(h, P, hsq, psq, n, H, k);
  k_msort<<<dim3(n / 64, (k + 63) / 64), dim3(256), 0, stream>>>(h, P, hsq, psq, perm, Ms, n, H, k);
  k_sink<<<NT, 1024, 0, stream>>>(Ms, meta, plD, plE, uF, vF, k, tm_last);
  k_epi<<<n, 256, 0, stream>>>(Ms, uF, vF, perm, tys, (float*)d_out, n, k);
}